// Round 5
// baseline (164.003 us; speedup 1.0000x reference)
//
#include <hip/hip_runtime.h>
#include <math.h>

// Reduction layout (21 accumulators, stored padded to stride 24):
//   [0..5]   Sx[c]   = sum output[:,c]
//   [6..11]  Sxx[c]  = sum output[:,c]^2
//   [12..17] Sxy[c]  = sum output[:,c]*label
//   [18]     Sy      = sum label
//   [19]     Syy     = sum label^2
//   [20]     Hsum    = sum_rows sum_c huber*alpha
static constexpr int BLOCK      = 256;
static constexpr int WAVES      = BLOCK / 64;           // 4
static constexpr int NACC       = 21;
static constexpr int PSTRIDE    = 24;                   // padded partial stride
static constexpr int WTILE_ROWS = 128;                  // rows per wave-tile
static constexpr int WTILE_F4   = WTILE_ROWS * 6 / 4;   // 192 float4 = 3 KB
static constexpr int MAXBLOCKS  = 2048;

__device__ __forceinline__ void async_f4(const float4* g, float4* l) {
    __builtin_amdgcn_global_load_lds(
        (const __attribute__((address_space(1))) void*)g,
        (__attribute__((address_space(3))) void*)l,
        16, 0, 0);
}
__device__ __forceinline__ void async_f1(const float* g, float* l) {
    __builtin_amdgcn_global_load_lds(
        (const __attribute__((address_space(1))) void*)g,
        (__attribute__((address_space(3))) void*)l,
        4, 0, 0);
}

__device__ __forceinline__ float fast_tanh_sq(float d) {
    // tanh(d) = 1 - 2/(exp(2d)+1); squared.
    float e = __expf(2.0f * d);
    float r = __builtin_amdgcn_rcpf(e + 1.0f);
    float t = 1.0f - 2.0f * r;
    return t * t;
}

__device__ __forceinline__ void row_accum(float acc[NACC], const float x[6], float y) {
    acc[18] += y;
    acc[19] += y * y;
    float rowh = 0.0f;
#pragma unroll
    for (int c = 0; c < 6; ++c) {
        const float xv = x[c];
        acc[c]      += xv;
        acc[6 + c]  += xv * xv;
        acc[12 + c] += xv * y;
        const float d   = xv - y;
        const float hub = 4.0f * (__builtin_amdgcn_sqrtf(1.0f + 0.25f * d * d) - 1.0f);
        const float al  = (c < 5) ? (0.2f * fast_tanh_sq(d)) : 1.0f;
        rowh += hub * al;
    }
    acc[20] += rowh;
}

__device__ __forceinline__ void chunk_accum(float acc[NACC],
                                            const float4 a, const float4 b,
                                            const float4 c, const float2 y2) {
    const float r0v[6] = {a.x, a.y, a.z, a.w, b.x, b.y};
    const float r1v[6] = {b.z, b.w, c.x, c.y, c.z, c.w};
    row_accum(acc, r0v, y2.x);
    row_accum(acc, r1v, y2.y);
}

__global__ __launch_bounds__(BLOCK) void huber_partial_kernel(
    const float* __restrict__ out6,
    const float* __restrict__ lab,
    float* __restrict__ part,
    int n)
{
    // Wave-private double-buffered staging: no __syncthreads in the stream loop.
    __shared__ __align__(16) float4 sdat[WAVES][2][WTILE_F4];   // 24 KB
    __shared__ __align__(16) float  slab[WAVES][2][WTILE_ROWS]; // 4 KB
    __shared__ float red[WAVES][NACC];

    float acc[NACC];
#pragma unroll
    for (int k = 0; k < NACC; ++k) acc[k] = 0.0f;

    const int t = threadIdx.x;
    const int w = t >> 6;
    const int l = t & 63;

    const long long tiles = (long long)n / WTILE_ROWS;
    const int nws = gridDim.x * WAVES;
    const float4* gsrc = reinterpret_cast<const float4*>(out6);

    auto issue = [&](long long tile, int b) {
        const float4* g = gsrc + tile * WTILE_F4;
        async_f4(g + l,       &sdat[w][b][l]);
        async_f4(g + 64 + l,  &sdat[w][b][64 + l]);
        async_f4(g + 128 + l, &sdat[w][b][128 + l]);
        const float* gl = lab + tile * WTILE_ROWS;
        async_f1(gl + l,      &slab[w][b][l]);
        async_f1(gl + 64 + l, &slab[w][b][64 + l]);
    };

    long long tc = (long long)blockIdx.x * WAVES + w;
    int buf = 0;
    if (tc < tiles) issue(tc, buf);

    while (tc < tiles) {
        const long long tn = tc + nws;
        if (tn < tiles) {
            issue(tn, buf ^ 1);
            // Wait for current tile's 5 loads; leave next tile's 5 in flight.
            asm volatile("s_waitcnt vmcnt(5)" ::: "memory");
        } else {
            asm volatile("s_waitcnt vmcnt(0)" ::: "memory");
        }
        const float4 a = sdat[w][buf][3 * l + 0];
        const float4 b = sdat[w][buf][3 * l + 1];
        const float4 c = sdat[w][buf][3 * l + 2];
        const float2 y2 = make_float2(slab[w][buf][2 * l],
                                      slab[w][buf][2 * l + 1]);
        chunk_accum(acc, a, b, c, y2);
        buf ^= 1;
        tc = tn;
    }

    // Tail rows [tiles*128, n): block 0 / wave 0, scalar (n=4M -> empty).
    if (blockIdx.x == 0 && w == 0) {
        for (long long r = tiles * WTILE_ROWS + l; r < n; r += 64) {
            float xr[6];
#pragma unroll
            for (int c = 0; c < 6; ++c) xr[c] = out6[r * 6 + c];
            row_accum(acc, xr, lab[r]);
        }
    }

    // Wave shuffle reduction.
#pragma unroll
    for (int k = 0; k < NACC; ++k) {
        float v = acc[k];
#pragma unroll
        for (int off = 32; off > 0; off >>= 1)
            v += __shfl_down(v, off, 64);
        acc[k] = v;
    }
    if (l == 0) {
#pragma unroll
        for (int k = 0; k < NACC; ++k) red[w][k] = acc[k];
    }
    __syncthreads();
    if (t < NACC) {
        float s = 0.0f;
#pragma unroll
        for (int ww = 0; ww < WAVES; ++ww) s += red[ww][t];
        part[(size_t)blockIdx.x * PSTRIDE + t] = s;
    }
}

__global__ __launch_bounds__(BLOCK) void huber_final_kernel(
    const float* __restrict__ part, int nblocks, int n, float* __restrict__ out)
{
    __shared__ double sred[BLOCK / 64][NACC];

    double acc[NACC];
#pragma unroll
    for (int k = 0; k < NACC; ++k) acc[k] = 0.0;

    for (int b = threadIdx.x; b < nblocks; b += BLOCK) {
        const float* p = part + (size_t)b * PSTRIDE;
        const float4* p4 = reinterpret_cast<const float4*>(p);
#pragma unroll
        for (int q = 0; q < 5; ++q) {
            const float4 v = p4[q];
            acc[q * 4 + 0] += (double)v.x;
            acc[q * 4 + 1] += (double)v.y;
            acc[q * 4 + 2] += (double)v.z;
            acc[q * 4 + 3] += (double)v.w;
        }
        acc[20] += (double)p[20];
    }

#pragma unroll
    for (int k = 0; k < NACC; ++k) {
        double v = acc[k];
#pragma unroll
        for (int off = 32; off > 0; off >>= 1)
            v += __shfl_down(v, off, 64);
        acc[k] = v;
    }

    const int wave = threadIdx.x >> 6;
    const int lane = threadIdx.x & 63;
    if (lane == 0) {
#pragma unroll
        for (int k = 0; k < NACC; ++k) sred[wave][k] = acc[k];
    }
    __syncthreads();

    if (threadIdx.x == 0) {
        double tot[NACC];
#pragma unroll
        for (int k = 0; k < NACC; ++k) {
            double s = 0.0;
#pragma unroll
            for (int w = 0; w < BLOCK / 64; ++w) s += sred[w][k];
            tot[k] = s;
        }

        const double dn  = (double)n;
        const double Sy  = tot[18];
        const double Syy = tot[19];
        const double vary = Syy - Sy * Sy / dn;
        double pc[6];
#pragma unroll
        for (int c = 0; c < 6; ++c) {
            const double Sx  = tot[c];
            const double Sxx = tot[6 + c];
            const double Sxy = tot[12 + c];
            const double cov  = Sxy - Sx * Sy / dn;
            const double varx = Sxx - Sx * Sx / dn;
            pc[c] = cov / (sqrt(varx) * sqrt(vary));
        }
        const double loss_old = tot[20] / dn;
        const double s = 5.0 - pc[0] - pc[1] - pc[2] - pc[3] - pc[4];
        double pen = 0.0;
#pragma unroll
        for (int c = 0; c < 5; ++c) pen += (1.0 - pc[c]) * (1.0 - pc[c]);
        pen /= s;
        const double loss = loss_old + pen + (1.0 - pc[5]);
        out[0] = (float)loss;
    }
}

extern "C" void kernel_launch(void* const* d_in, const int* in_sizes, int n_in,
                              void* d_out, int out_size, void* d_ws, size_t ws_size,
                              hipStream_t stream) {
    const float* out6 = (const float*)d_in[0];  // (n,6) f32 row-major
    const float* lab  = (const float*)d_in[1];  // (n,1) f32
    float* out = (float*)d_out;
    const int n = in_sizes[1];

    const long long tiles = (long long)n / WTILE_ROWS;
    long long want = (tiles + WAVES - 1) / WAVES;
    if (want < 1) want = 1;

    int nblocks = MAXBLOCKS;
    const int maxb = (int)(ws_size / (PSTRIDE * sizeof(float)));
    if (nblocks > maxb) nblocks = maxb;
    if ((long long)nblocks > want) nblocks = (int)want;
    if (nblocks < 1) nblocks = 1;

    float* part = (float*)d_ws;
    hipLaunchKernelGGL(huber_partial_kernel, dim3(nblocks), dim3(BLOCK), 0, stream,
                       out6, lab, part, n);
    hipLaunchKernelGGL(huber_final_kernel, dim3(1), dim3(BLOCK), 0, stream,
                       part, nblocks, n, out);
}